// Round 1
// baseline (1505.036 us; speedup 1.0000x reference)
//
#include <hip/hip_runtime.h>

#define HS 32
#define NBLKA 1024

__device__ __forceinline__ unsigned encf(float x) {
    unsigned u = __float_as_uint(x);
    return (u & 0x80000000u) ? ~u : (u | 0x80000000u);
}
__device__ __forceinline__ float decf(unsigned u) {
    u = (u & 0x80000000u) ? (u & 0x7FFFFFFFu) : ~u;
    return __uint_as_float(u);
}

// ---------- CSR build ----------
__global__ void hist_k(const int* __restrict__ dst, int E, int* __restrict__ rowptr) {
    for (int e = blockIdx.x * blockDim.x + threadIdx.x; e < E; e += gridDim.x * blockDim.x)
        atomicAdd(&rowptr[dst[e] + 1], 1);
}

__global__ void scanA_k(int* __restrict__ data, int total, int* __restrict__ chunkTot) {
    __shared__ int sd[256];
    int tid = threadIdx.x;
    int base = blockIdx.x * 2048 + tid * 8;
    int v[8]; int s = 0;
#pragma unroll
    for (int r = 0; r < 8; r++) {
        int idx = base + r;
        int x = (idx < total) ? data[idx] : 0;
        s += x; v[r] = s;
    }
    sd[tid] = s; __syncthreads();
    for (int off = 1; off < 256; off <<= 1) {
        int x = (tid >= off) ? sd[tid - off] : 0;
        __syncthreads();
        sd[tid] += x;
        __syncthreads();
    }
    int prev = (tid > 0) ? sd[tid - 1] : 0;
#pragma unroll
    for (int r = 0; r < 8; r++) {
        int idx = base + r;
        if (idx < total) data[idx] = v[r] + prev;
    }
    if (tid == 255) chunkTot[blockIdx.x] = sd[255];
}

__global__ void scanB_k(const int* __restrict__ chunkTot, int nchunk, int* __restrict__ chunkOff) {
    __shared__ int sd[256];
    int tid = threadIdx.x;
    int v = (tid < nchunk) ? chunkTot[tid] : 0;
    sd[tid] = v; __syncthreads();
    for (int off = 1; off < 256; off <<= 1) {
        int x = (tid >= off) ? sd[tid - off] : 0;
        __syncthreads();
        sd[tid] += x;
        __syncthreads();
    }
    if (tid < nchunk) chunkOff[tid] = sd[tid] - v;
}

__global__ void scanC_k(int* __restrict__ data, int total, const int* __restrict__ chunkOff,
                        int* __restrict__ fill, int Nn) {
    int off = chunkOff[blockIdx.x];
    int base = blockIdx.x * 2048 + threadIdx.x * 8;
#pragma unroll
    for (int r = 0; r < 8; r++) {
        int idx = base + r;
        if (idx < total) {
            int val = data[idx] + off;
            data[idx] = val;
            if (idx < Nn) fill[idx] = val;
        }
    }
}

__global__ void scatter_k(const int* __restrict__ ei, const int* __restrict__ ety, int E,
                          int* __restrict__ fill, unsigned* __restrict__ sorted) {
    for (int e = blockIdx.x * blockDim.x + threadIdx.x; e < E; e += gridDim.x * blockDim.x) {
        int s = ei[e];
        int d = ei[E + e];
        int ty = ety[e];
        int pos = atomicAdd(&fill[d], 1);
        sorted[pos] = (unsigned)s | ((unsigned)ty << 20);
    }
}

__global__ void initpool_k(unsigned* __restrict__ maxb, float* __restrict__ sumb, int n) {
    int i = blockIdx.x * blockDim.x + threadIdx.x;
    if (i < n) { maxb[i] = 0x007FFFFFu; sumb[i] = 0.f; }  // enc(-inf)
}

// ---------- layer A: aggregate + z@W1+b1 + BN partial stats ----------
__global__ __launch_bounds__(256) void layerA_k(
    const float* __restrict__ hin, const int* __restrict__ rowptr,
    const unsigned* __restrict__ sorted, const float* __restrict__ emb,
    const float* __restrict__ W1, const float* __restrict__ b1,
    float* __restrict__ tout, float* __restrict__ partial, int Nn)
{
    int tid = threadIdx.x;
    int j = tid & 31, grp = tid >> 5;
    float w1c[32];
#pragma unroll
    for (int k = 0; k < 32; k++) w1c[k] = W1[k * 32 + j];
    float b1j = b1[j];
    float e0v = emb[j], e1v = emb[32 + j];
    float bsum = 0.f, bsq = 0.f;

    for (int n = blockIdx.x * 8 + grp; n < Nn; n += gridDim.x * 8) {
        float acc = hin[n * HS + j];
        int es = rowptr[n], ee = rowptr[n + 1];
        for (int e = es; e < ee; e += 32) {
            int r = ee - e; if (r > 32) r = 32;
            unsigned pv = (j < r) ? sorted[e + j] : 0u;
#pragma unroll
            for (int k = 0; k < 32; k++) {
                unsigned p = (unsigned)__shfl((int)pv, k, 32);
                int s = (int)(p & 0xFFFFFu);
                float hs = hin[s * HS + j];          // invalid lanes read node 0 (L1-hot), masked below
                float ev = (p >> 20) ? e1v : e0v;
                float rl = fmaxf(hs + ev, 0.f);
                acc += (k < r) ? rl : 0.f;
            }
        }
        // t_j = b1_j + sum_k z_k * W1[k][j]
        float t = b1j;
#pragma unroll
        for (int k = 0; k < 32; k++) t = fmaf(__shfl(acc, k, 32), w1c[k], t);
        tout[n * 32 + j] = t;
        bsum += t; bsq += t * t;
    }

    __shared__ float ls[8][32], lq[8][32];
    ls[grp][j] = bsum; lq[grp][j] = bsq;
    __syncthreads();
    if (tid < 32) {
        float s = 0.f, q = 0.f;
#pragma unroll
        for (int r = 0; r < 8; r++) { s += ls[r][tid]; q += lq[r][tid]; }
        partial[blockIdx.x * 64 + tid] = s;
        partial[blockIdx.x * 64 + 32 + tid] = q;
    }
}

// ---------- BN stat reduce -> a, c ----------
__global__ void bnred_k(const float* __restrict__ partial, int nblk,
                        const float* __restrict__ gamma, const float* __restrict__ beta,
                        float* __restrict__ bn_ac, float invN)
{
    __shared__ float sd[256];
    __shared__ float tot[64];
    int tid = threadIdx.x;
    int j = tid >> 2, sub = tid & 3;
    float s = 0.f;
    for (int b = sub; b < nblk; b += 4) s += partial[b * 64 + j];
    sd[tid] = s; __syncthreads();
    if (sub == 0) tot[j] = sd[tid] + sd[tid + 1] + sd[tid + 2] + sd[tid + 3];
    __syncthreads();
    if (tid < 32) {
        float mu = tot[tid] * invN;
        float var = tot[32 + tid] * invN - mu * mu;
        float a = gamma[tid] * rsqrtf(var + 1e-5f);
        bn_ac[tid] = a;
        bn_ac[32 + tid] = beta[tid] - a * mu;
    }
}

// ---------- layer B: relu(bn(t)) @ W2 + b2 (+relu) ----------
__global__ __launch_bounds__(256) void layerB32_k(
    const float* __restrict__ tin, const float* __restrict__ bn_ac,
    const float* __restrict__ W2, const float* __restrict__ b2,
    float* __restrict__ hout, int Nn, int doRelu)
{
    int tid = threadIdx.x;
    int j = tid & 31, grp = tid >> 5;
    float a = bn_ac[j], c = bn_ac[32 + j];
    float wc[32];
#pragma unroll
    for (int k = 0; k < 32; k++) wc[k] = W2[k * 32 + j];
    float bj = b2[j];
    for (int n = blockIdx.x * 8 + grp; n < Nn; n += gridDim.x * 8) {
        float t = tin[n * 32 + j];
        float u = fmaxf(fmaf(a, t, c), 0.f);
        float o = bj;
#pragma unroll
        for (int k = 0; k < 32; k++) o = fmaf(__shfl(u, k, 32), wc[k], o);
        hout[n * 32 + j] = doRelu ? fmaxf(o, 0.f) : o;
    }
}

__global__ __launch_bounds__(256) void layerB64_k(
    const float* __restrict__ tin, const float* __restrict__ bn_ac,
    const float* __restrict__ W2, const float* __restrict__ b2,
    float* __restrict__ hout, int Nn)
{
    int tid = threadIdx.x;
    int j = tid & 31, grp = tid >> 5;
    float a = bn_ac[j], c = bn_ac[32 + j];
    float wlo[32], whi[32];
#pragma unroll
    for (int k = 0; k < 32; k++) { wlo[k] = W2[k * 64 + j]; whi[k] = W2[k * 64 + 32 + j]; }
    float blo = b2[j], bhi = b2[32 + j];
    for (int n = blockIdx.x * 8 + grp; n < Nn; n += gridDim.x * 8) {
        float t = tin[n * 32 + j];
        float u = fmaxf(fmaf(a, t, c), 0.f);
        float olo = blo, ohi = bhi;
#pragma unroll
        for (int k = 0; k < 32; k++) {
            float uk = __shfl(u, k, 32);
            olo = fmaf(uk, wlo[k], olo);
            ohi = fmaf(uk, whi[k], ohi);
        }
        hout[n * 64 + j] = olo;        // no final relu (conv5)
        hout[n * 64 + 32 + j] = ohi;
    }
}

// ---------- pooling ----------
__global__ void pool1_k(const float* __restrict__ h5, const int* __restrict__ batch,
                        unsigned* __restrict__ maxb, float* __restrict__ sumb, int Nn)
{
    int ch = threadIdx.x & 63, slot = threadIdx.x >> 6;
    int base = blockIdx.x * 256 + slot * 64;
    int g = -1; float mx = 0.f, sm = 0.f;
    for (int i = 0; i < 64; i++) {
        int node = base + i;
        if (node >= Nn) break;
        int gn = batch[node];
        float v = h5[node * 64 + ch];
        if (gn != g) {
            if (g >= 0) { atomicMax(&maxb[g * 64 + ch], encf(mx)); atomicAdd(&sumb[g * 64 + ch], sm); }
            g = gn; mx = v; sm = v;
        } else { mx = fmaxf(mx, v); sm += v; }
    }
    if (g >= 0) { atomicMax(&maxb[g * 64 + ch], encf(mx)); atomicAdd(&sumb[g * 64 + ch], sm); }
}

__global__ void final_k(const unsigned* __restrict__ maxb, const float* __restrict__ sumb,
                        const int* __restrict__ batch, int Nn, float* __restrict__ out)
{
    int g = blockIdx.x, tid = threadIdx.x;
    int a = 0, b = Nn;
    while (a < b) { int m = (a + b) >> 1; if (batch[m] < g) a = m + 1; else b = m; }
    int lo0 = a;
    a = 0; b = Nn;
    while (a < b) { int m = (a + b) >> 1; if (batch[m] < g + 1) a = m + 1; else b = m; }
    int hi0 = a;
    float inv = 1.f / fmaxf((float)(hi0 - lo0), 1.f);
    if (tid < 64) out[g * 128 + tid] = decf(maxb[g * 64 + tid]);
    else          out[g * 128 + tid] = sumb[g * 64 + (tid - 64)] * inv;
}

extern "C" void kernel_launch(void* const* d_in, const int* in_sizes, int n_in,
                              void* d_out, int out_size, void* d_ws, size_t ws_size,
                              hipStream_t stream) {
    const float* x    = (const float*)d_in[0];
    const int*   ei   = (const int*)d_in[1];
    const int*   ety  = (const int*)d_in[2];
    const int*   batch= (const int*)d_in[3];
    const float* emb  = (const float*)d_in[4];
    const float* W1s  = (const float*)d_in[5];
    const float* b1s  = (const float*)d_in[6];
    const float* g1s  = (const float*)d_in[7];
    const float* be1s = (const float*)d_in[8];
    const float* W2s  = (const float*)d_in[9];
    const float* b2s  = (const float*)d_in[10];
    const float* w15  = (const float*)d_in[11];
    const float* b15  = (const float*)d_in[12];
    const float* g5   = (const float*)d_in[13];
    const float* be5  = (const float*)d_in[14];
    const float* w25  = (const float*)d_in[15];
    const float* b25  = (const float*)d_in[16];

    int N = in_sizes[0] / 32;
    int E = in_sizes[1] / 2;
    int G = out_size / 128;

    char* wsb = (char*)d_ws;
    size_t o = 0;
    float*    h5     = (float*)(wsb + o); o += (size_t)N * 64 * 4;
    float*    tb     = (float*)(wsb + o); o += (size_t)N * 32 * 4;
    int*      rowptr = (int*)(wsb + o);   o += ((size_t)N + 2) * 4;
    int*      fill   = (int*)(wsb + o);   o += (size_t)N * 4;
    unsigned* sorted = (unsigned*)(wsb + o); o += (size_t)E * 4;
    int*      chunkTot = (int*)(wsb + o); o += 1024;
    int*      chunkOff = (int*)(wsb + o); o += 1024;
    float*    partial  = (float*)(wsb + o); o += (size_t)NBLKA * 64 * 4;
    float*    bn_ac    = (float*)(wsb + o); o += 64 * 4;
    unsigned* maxb     = (unsigned*)(wsb + o); o += (size_t)G * 64 * 4;
    float*    sumb     = (float*)(wsb + o); o += (size_t)G * 64 * 4;

    // ---- CSR build (per call; deterministic work) ----
    hipMemsetAsync(rowptr, 0, ((size_t)N + 1) * sizeof(int), stream);
    hist_k<<<2048, 256, 0, stream>>>(ei + E, E, rowptr);
    int total = N + 1;
    int nchunk = (total + 2047) / 2048;
    scanA_k<<<nchunk, 256, 0, stream>>>(rowptr, total, chunkTot);
    scanB_k<<<1, 256, 0, stream>>>(chunkTot, nchunk, chunkOff);
    scanC_k<<<nchunk, 256, 0, stream>>>(rowptr, total, chunkOff, fill, N);
    scatter_k<<<2048, 256, 0, stream>>>(ei, ety, E, fill, sorted);
    initpool_k<<<(G * 64 + 255) / 256, 256, 0, stream>>>(maxb, sumb, G * 64);

    // ---- 5 GINE layers ----
    const float* hin = x;
    for (int L = 0; L < 5; ++L) {
        const float* W1 = (L < 4) ? W1s + L * 1024 : w15;
        const float* b1 = (L < 4) ? b1s + L * 32  : b15;
        const float* ga = (L < 4) ? g1s + L * 32  : g5;
        const float* be = (L < 4) ? be1s + L * 32 : be5;
        const float* W2 = (L < 4) ? W2s + L * 1024 : w25;
        const float* b2 = (L < 4) ? b2s + L * 32  : b25;

        layerA_k<<<NBLKA, 256, 0, stream>>>(hin, rowptr, sorted, emb, W1, b1, tb, partial, N);
        bnred_k<<<1, 256, 0, stream>>>(partial, NBLKA, ga, be, bn_ac, 1.f / (float)N);
        if (L < 4) layerB32_k<<<1024, 256, 0, stream>>>(tb, bn_ac, W2, b2, h5, N, 1);
        else       layerB64_k<<<1024, 256, 0, stream>>>(tb, bn_ac, W2, b2, h5, N);
        hin = h5;
    }

    // ---- pooling ----
    pool1_k<<<(N + 255) / 256, 256, 0, stream>>>(h5, batch, maxb, sumb, N);
    final_k<<<G, 128, 0, stream>>>(maxb, sumb, batch, N, (float*)d_out);
}

// Round 2
// 1344.634 us; speedup vs baseline: 1.1193x; 1.1193x over previous
//
#include <hip/hip_runtime.h>

#define HS 32
#define NBLKA 1024

__device__ __forceinline__ unsigned encf(float x) {
    unsigned u = __float_as_uint(x);
    return (u & 0x80000000u) ? ~u : (u | 0x80000000u);
}
__device__ __forceinline__ float decf(unsigned u) {
    u = (u & 0x80000000u) ? (u & 0x7FFFFFFFu) : ~u;
    return __uint_as_float(u);
}

// ================= CSR build: locality-staged counting sort =================

// pass A: bucket histogram (bucket = dst >> shift, <=256 buckets)
__global__ __launch_bounds__(256) void passA_k(const int* __restrict__ dst, int E,
                                               int* __restrict__ bucketCnt, int shift) {
    __shared__ int hist[256];
    hist[threadIdx.x] = 0;
    __syncthreads();
    int base = blockIdx.x * 4096;
#pragma unroll
    for (int r = 0; r < 16; r++) {
        int i = base + threadIdx.x + r * 256;
        if (i < E) atomicAdd(&hist[dst[i] >> shift], 1);
    }
    __syncthreads();
    int h = hist[threadIdx.x];
    if (h) atomicAdd(&bucketCnt[threadIdx.x], h);
}

// bucket scan: bucketOff (exclusive, 257 entries), bucketFill = copy
__global__ void bscan_k(const int* __restrict__ bucketCnt, int* __restrict__ bucketOff,
                        int* __restrict__ bucketFill) {
    __shared__ int sd[256];
    int tid = threadIdx.x;
    int v = bucketCnt[tid];
    sd[tid] = v; __syncthreads();
    for (int off = 1; off < 256; off <<= 1) {
        int x = (tid >= off) ? sd[tid - off] : 0;
        __syncthreads();
        sd[tid] += x;
        __syncthreads();
    }
    int incl = sd[tid];
    bucketOff[tid + 1] = incl;
    bucketFill[tid] = incl - v;
    if (tid == 0) bucketOff[0] = 0;
}

// pass B: per-block LDS counting sort into buckets + fused per-node rowptr histogram
__global__ __launch_bounds__(256) void passB_k(const int* __restrict__ ei,
                                               const int* __restrict__ ety, int E,
                                               int* __restrict__ bucketFill,
                                               unsigned long long* __restrict__ binned,
                                               int* __restrict__ rowptr, int shift) {
    __shared__ unsigned long long stage[4096];
    __shared__ int hist[256], sd[256], cursor[256], rebase[256];
    int tid = threadIdx.x;
    int base = blockIdx.x * 4096;
    hist[tid] = 0;
    __syncthreads();

    unsigned long long ent[16];
    int bk[16];
#pragma unroll
    for (int r = 0; r < 16; r++) {
        int i = base + tid + r * 256;
        if (i < E) {
            int s = ei[i];
            int d = ei[E + i];
            int t = ety[i];
            ent[r] = ((unsigned long long)d << 21) | ((unsigned)t << 20) | (unsigned)s;
            bk[r] = d >> shift;
            atomicAdd(&hist[bk[r]], 1);
        } else bk[r] = -1;
    }
    __syncthreads();

    int h = hist[tid];
    sd[tid] = h; __syncthreads();
    for (int off = 1; off < 256; off <<= 1) {
        int x = (tid >= off) ? sd[tid - off] : 0;
        __syncthreads();
        sd[tid] += x;
        __syncthreads();
    }
    int excl = sd[tid] - h;
    cursor[tid] = excl;
    int gb = 0;
    if (h > 0) gb = atomicAdd(&bucketFill[tid], h);
    rebase[tid] = gb - excl;
    __syncthreads();

#pragma unroll
    for (int r = 0; r < 16; r++) {
        if (bk[r] >= 0) {
            int p = atomicAdd(&cursor[bk[r]], 1);
            stage[p] = ent[r];
        }
    }
    __syncthreads();

    int cnt = E - base; if (cnt > 4096) cnt = 4096;
    for (int i = tid; i < cnt; i += 256) {
        unsigned long long e = stage[i];
        int d = (int)(e >> 21);
        binned[rebase[d >> shift] + i] = e;
        atomicAdd(&rowptr[d + 1], 1);
    }
}

// pass C: one block per bucket -> final node-sorted edge list (L2-local)
__global__ __launch_bounds__(256) void passC_k(const unsigned long long* __restrict__ binned,
                                               const int* __restrict__ bucketOff,
                                               int* __restrict__ fill,
                                               unsigned* __restrict__ sorted) {
    int b = blockIdx.x;
    int s = bucketOff[b], e = bucketOff[b + 1];
    for (int i = s + threadIdx.x; i < e; i += 256) {
        unsigned long long en = binned[i];
        int d = (int)(en >> 21);
        int pos = atomicAdd(&fill[d], 1);
        sorted[pos] = (unsigned)(en & 0x1FFFFFu);
    }
}

// ---------- rowptr scan (3-kernel) ----------
__global__ void scanA_k(int* __restrict__ data, int total, int* __restrict__ chunkTot) {
    __shared__ int sd[256];
    int tid = threadIdx.x;
    int base = blockIdx.x * 2048 + tid * 8;
    int v[8]; int s = 0;
#pragma unroll
    for (int r = 0; r < 8; r++) {
        int idx = base + r;
        int x = (idx < total) ? data[idx] : 0;
        s += x; v[r] = s;
    }
    sd[tid] = s; __syncthreads();
    for (int off = 1; off < 256; off <<= 1) {
        int x = (tid >= off) ? sd[tid - off] : 0;
        __syncthreads();
        sd[tid] += x;
        __syncthreads();
    }
    int prev = (tid > 0) ? sd[tid - 1] : 0;
#pragma unroll
    for (int r = 0; r < 8; r++) {
        int idx = base + r;
        if (idx < total) data[idx] = v[r] + prev;
    }
    if (tid == 255) chunkTot[blockIdx.x] = sd[255];
}

__global__ void scanB_k(const int* __restrict__ chunkTot, int nchunk, int* __restrict__ chunkOff) {
    __shared__ int sd[256];
    int tid = threadIdx.x;
    int v = (tid < nchunk) ? chunkTot[tid] : 0;
    sd[tid] = v; __syncthreads();
    for (int off = 1; off < 256; off <<= 1) {
        int x = (tid >= off) ? sd[tid - off] : 0;
        __syncthreads();
        sd[tid] += x;
        __syncthreads();
    }
    if (tid < nchunk) chunkOff[tid] = sd[tid] - v;
}

__global__ void scanC_k(int* __restrict__ data, int total, const int* __restrict__ chunkOff,
                        int* __restrict__ fill, int Nn) {
    int off = chunkOff[blockIdx.x];
    int base = blockIdx.x * 2048 + threadIdx.x * 8;
#pragma unroll
    for (int r = 0; r < 8; r++) {
        int idx = base + r;
        if (idx < total) {
            int val = data[idx] + off;
            data[idx] = val;
            if (idx < Nn) fill[idx] = val;
        }
    }
}

__global__ void initpool_k(unsigned* __restrict__ maxb, float* __restrict__ sumb, int n) {
    int i = blockIdx.x * blockDim.x + threadIdx.x;
    if (i < n) { maxb[i] = 0x007FFFFFu; sumb[i] = 0.f; }  // enc(-inf)
}

// ---------- layer A: aggregate + z@W1+b1 + BN partial stats ----------
__global__ __launch_bounds__(256) void layerA_k(
    const float* __restrict__ hin, const int* __restrict__ rowptr,
    const unsigned* __restrict__ sorted, const float* __restrict__ emb,
    const float* __restrict__ W1, const float* __restrict__ b1,
    float* __restrict__ tout, float* __restrict__ partial, int Nn)
{
    int tid = threadIdx.x;
    int j = tid & 31, grp = tid >> 5;
    float w1c[32];
#pragma unroll
    for (int k = 0; k < 32; k++) w1c[k] = W1[k * 32 + j];
    float b1j = b1[j];
    float e0v = emb[j], e1v = emb[32 + j];
    float bsum = 0.f, bsq = 0.f;

    for (int n = blockIdx.x * 8 + grp; n < Nn; n += gridDim.x * 8) {
        float acc = hin[n * HS + j];
        int es = rowptr[n], ee = rowptr[n + 1];
        for (int e = es; e < ee; e += 32) {
            int r = ee - e; if (r > 32) r = 32;
            unsigned pv = (j < r) ? sorted[e + j] : 0u;
#pragma unroll
            for (int k = 0; k < 32; k++) {
                unsigned p = (unsigned)__shfl((int)pv, k, 32);
                int s = (int)(p & 0xFFFFFu);
                float hs = hin[s * HS + j];
                float ev = (p >> 20) ? e1v : e0v;
                float rl = fmaxf(hs + ev, 0.f);
                acc += (k < r) ? rl : 0.f;
            }
        }
        float t = b1j;
#pragma unroll
        for (int k = 0; k < 32; k++) t = fmaf(__shfl(acc, k, 32), w1c[k], t);
        tout[n * 32 + j] = t;
        bsum += t; bsq += t * t;
    }

    __shared__ float ls[8][32], lq[8][32];
    ls[grp][j] = bsum; lq[grp][j] = bsq;
    __syncthreads();
    if (tid < 32) {
        float s = 0.f, q = 0.f;
#pragma unroll
        for (int r = 0; r < 8; r++) { s += ls[r][tid]; q += lq[r][tid]; }
        partial[blockIdx.x * 64 + tid] = s;
        partial[blockIdx.x * 64 + 32 + tid] = q;
    }
}

// ---------- BN stat reduce -> a, c ----------
__global__ void bnred_k(const float* __restrict__ partial, int nblk,
                        const float* __restrict__ gamma, const float* __restrict__ beta,
                        float* __restrict__ bn_ac, float invN)
{
    __shared__ float sd[256];
    __shared__ float tot[64];
    int tid = threadIdx.x;
    int j = tid >> 2, sub = tid & 3;
    float s = 0.f;
    for (int b = sub; b < nblk; b += 4) s += partial[b * 64 + j];
    sd[tid] = s; __syncthreads();
    if (sub == 0) tot[j] = sd[tid] + sd[tid + 1] + sd[tid + 2] + sd[tid + 3];
    __syncthreads();
    if (tid < 32) {
        float mu = tot[tid] * invN;
        float var = tot[32 + tid] * invN - mu * mu;
        float a = gamma[tid] * rsqrtf(var + 1e-5f);
        bn_ac[tid] = a;
        bn_ac[32 + tid] = beta[tid] - a * mu;
    }
}

// ---------- layer B: relu(bn(t)) @ W2 + b2 (+relu) ----------
__global__ __launch_bounds__(256) void layerB32_k(
    const float* __restrict__ tin, const float* __restrict__ bn_ac,
    const float* __restrict__ W2, const float* __restrict__ b2,
    float* __restrict__ hout, int Nn, int doRelu)
{
    int tid = threadIdx.x;
    int j = tid & 31, grp = tid >> 5;
    float a = bn_ac[j], c = bn_ac[32 + j];
    float wc[32];
#pragma unroll
    for (int k = 0; k < 32; k++) wc[k] = W2[k * 32 + j];
    float bj = b2[j];
    for (int n = blockIdx.x * 8 + grp; n < Nn; n += gridDim.x * 8) {
        float t = tin[n * 32 + j];
        float u = fmaxf(fmaf(a, t, c), 0.f);
        float o = bj;
#pragma unroll
        for (int k = 0; k < 32; k++) o = fmaf(__shfl(u, k, 32), wc[k], o);
        hout[n * 32 + j] = doRelu ? fmaxf(o, 0.f) : o;
    }
}

__global__ __launch_bounds__(256) void layerB64_k(
    const float* __restrict__ tin, const float* __restrict__ bn_ac,
    const float* __restrict__ W2, const float* __restrict__ b2,
    float* __restrict__ hout, int Nn)
{
    int tid = threadIdx.x;
    int j = tid & 31, grp = tid >> 5;
    float a = bn_ac[j], c = bn_ac[32 + j];
    float wlo[32], whi[32];
#pragma unroll
    for (int k = 0; k < 32; k++) { wlo[k] = W2[k * 64 + j]; whi[k] = W2[k * 64 + 32 + j]; }
    float blo = b2[j], bhi = b2[32 + j];
    for (int n = blockIdx.x * 8 + grp; n < Nn; n += gridDim.x * 8) {
        float t = tin[n * 32 + j];
        float u = fmaxf(fmaf(a, t, c), 0.f);
        float olo = blo, ohi = bhi;
#pragma unroll
        for (int k = 0; k < 32; k++) {
            float uk = __shfl(u, k, 32);
            olo = fmaf(uk, wlo[k], olo);
            ohi = fmaf(uk, whi[k], ohi);
        }
        hout[n * 64 + j] = olo;
        hout[n * 64 + 32 + j] = ohi;
    }
}

// ---------- pooling ----------
__global__ void pool1_k(const float* __restrict__ h5, const int* __restrict__ batch,
                        unsigned* __restrict__ maxb, float* __restrict__ sumb, int Nn)
{
    int ch = threadIdx.x & 63, slot = threadIdx.x >> 6;
    int base = blockIdx.x * 256 + slot * 64;
    int g = -1; float mx = 0.f, sm = 0.f;
    for (int i = 0; i < 64; i++) {
        int node = base + i;
        if (node >= Nn) break;
        int gn = batch[node];
        float v = h5[node * 64 + ch];
        if (gn != g) {
            if (g >= 0) { atomicMax(&maxb[g * 64 + ch], encf(mx)); atomicAdd(&sumb[g * 64 + ch], sm); }
            g = gn; mx = v; sm = v;
        } else { mx = fmaxf(mx, v); sm += v; }
    }
    if (g >= 0) { atomicMax(&maxb[g * 64 + ch], encf(mx)); atomicAdd(&sumb[g * 64 + ch], sm); }
}

__global__ void final_k(const unsigned* __restrict__ maxb, const float* __restrict__ sumb,
                        const int* __restrict__ batch, int Nn, float* __restrict__ out)
{
    int g = blockIdx.x, tid = threadIdx.x;
    int a = 0, b = Nn;
    while (a < b) { int m = (a + b) >> 1; if (batch[m] < g) a = m + 1; else b = m; }
    int lo0 = a;
    a = 0; b = Nn;
    while (a < b) { int m = (a + b) >> 1; if (batch[m] < g + 1) a = m + 1; else b = m; }
    int hi0 = a;
    float inv = 1.f / fmaxf((float)(hi0 - lo0), 1.f);
    if (tid < 64) out[g * 128 + tid] = decf(maxb[g * 64 + tid]);
    else          out[g * 128 + tid] = sumb[g * 64 + (tid - 64)] * inv;
}

extern "C" void kernel_launch(void* const* d_in, const int* in_sizes, int n_in,
                              void* d_out, int out_size, void* d_ws, size_t ws_size,
                              hipStream_t stream) {
    const float* x    = (const float*)d_in[0];
    const int*   ei   = (const int*)d_in[1];
    const int*   ety  = (const int*)d_in[2];
    const int*   batch= (const int*)d_in[3];
    const float* emb  = (const float*)d_in[4];
    const float* W1s  = (const float*)d_in[5];
    const float* b1s  = (const float*)d_in[6];
    const float* g1s  = (const float*)d_in[7];
    const float* be1s = (const float*)d_in[8];
    const float* W2s  = (const float*)d_in[9];
    const float* b2s  = (const float*)d_in[10];
    const float* w15  = (const float*)d_in[11];
    const float* b15  = (const float*)d_in[12];
    const float* g5   = (const float*)d_in[13];
    const float* be5  = (const float*)d_in[14];
    const float* w25  = (const float*)d_in[15];
    const float* b25  = (const float*)d_in[16];

    int N = in_sizes[0] / 32;
    int E = in_sizes[1] / 2;
    int G = out_size / 128;

    int shift = 0;
    while (((N - 1) >> shift) >= 256) shift++;
    int nbUsed = ((N - 1) >> shift) + 1;

    char* wsb = (char*)d_ws;
    size_t o = 0;
    size_t h5Bytes = (size_t)N * 64 * 4;
    size_t binBytes = (size_t)E * 8;
    size_t aliasBytes = h5Bytes > binBytes ? h5Bytes : binBytes;
    float*    h5     = (float*)(wsb + o);
    unsigned long long* binned = (unsigned long long*)(wsb + o);  // alias: dead before layerB0
    o += aliasBytes;
    float*    tb     = (float*)(wsb + o); o += (size_t)N * 32 * 4;
    int*      rowptr = (int*)(wsb + o);   o += ((size_t)N + 2) * 4;
    int*      fill   = (int*)(wsb + o);   o += (size_t)N * 4;
    unsigned* sorted = (unsigned*)(wsb + o); o += (size_t)E * 4;
    int*      chunkTot = (int*)(wsb + o); o += 1024;
    int*      chunkOff = (int*)(wsb + o); o += 1024;
    float*    partial  = (float*)(wsb + o); o += (size_t)NBLKA * 64 * 4;
    float*    bn_ac    = (float*)(wsb + o); o += 64 * 4;
    unsigned* maxb     = (unsigned*)(wsb + o); o += (size_t)G * 64 * 4;
    float*    sumb     = (float*)(wsb + o); o += (size_t)G * 64 * 4;
    int*      bucketCnt  = (int*)(wsb + o); o += 256 * 4;
    int*      bucketOff  = (int*)(wsb + o); o += 257 * 4;
    int*      bucketFill = (int*)(wsb + o); o += 256 * 4;

    // ---- CSR build via locality-staged counting sort ----
    hipMemsetAsync(rowptr, 0, ((size_t)N + 1) * sizeof(int), stream);
    hipMemsetAsync(bucketCnt, 0, 256 * sizeof(int), stream);

    int nblkE = (E + 4095) / 4096;
    passA_k<<<nblkE, 256, 0, stream>>>(ei + E, E, bucketCnt, shift);
    bscan_k<<<1, 256, 0, stream>>>(bucketCnt, bucketOff, bucketFill);
    passB_k<<<nblkE, 256, 0, stream>>>(ei, ety, E, bucketFill, binned, rowptr, shift);

    int total = N + 1;
    int nchunk = (total + 2047) / 2048;
    scanA_k<<<nchunk, 256, 0, stream>>>(rowptr, total, chunkTot);
    scanB_k<<<1, 256, 0, stream>>>(chunkTot, nchunk, chunkOff);
    scanC_k<<<nchunk, 256, 0, stream>>>(rowptr, total, chunkOff, fill, N);

    passC_k<<<nbUsed, 256, 0, stream>>>(binned, bucketOff, fill, sorted);
    initpool_k<<<(G * 64 + 255) / 256, 256, 0, stream>>>(maxb, sumb, G * 64);

    // ---- 5 GINE layers ----
    const float* hin = x;
    for (int L = 0; L < 5; ++L) {
        const float* W1 = (L < 4) ? W1s + L * 1024 : w15;
        const float* b1 = (L < 4) ? b1s + L * 32  : b15;
        const float* ga = (L < 4) ? g1s + L * 32  : g5;
        const float* be = (L < 4) ? be1s + L * 32 : be5;
        const float* W2 = (L < 4) ? W2s + L * 1024 : w25;
        const float* b2 = (L < 4) ? b2s + L * 32  : b25;

        layerA_k<<<NBLKA, 256, 0, stream>>>(hin, rowptr, sorted, emb, W1, b1, tb, partial, N);
        bnred_k<<<1, 256, 0, stream>>>(partial, NBLKA, ga, be, bn_ac, 1.f / (float)N);
        if (L < 4) layerB32_k<<<1024, 256, 0, stream>>>(tb, bn_ac, W2, b2, h5, N, 1);
        else       layerB64_k<<<1024, 256, 0, stream>>>(tb, bn_ac, W2, b2, h5, N);
        hin = h5;
    }

    // ---- pooling ----
    pool1_k<<<(N + 255) / 256, 256, 0, stream>>>(h5, batch, maxb, sumb, N);
    final_k<<<G, 128, 0, stream>>>(maxb, sumb, batch, N, (float*)d_out);
}

// Round 3
// 1121.429 us; speedup vs baseline: 1.3421x; 1.1990x over previous
//
#include <hip/hip_runtime.h>

#define NBLKA 1024

__device__ __forceinline__ unsigned encf(float x) {
    unsigned u = __float_as_uint(x);
    return (u & 0x80000000u) ? ~u : (u | 0x80000000u);
}
__device__ __forceinline__ float decf(unsigned u) {
    u = (u & 0x80000000u) ? (u & 0x7FFFFFFFu) : ~u;
    return __uint_as_float(u);
}

// ============ CSR build: deterministic matrix-scan counting sort ============

// pass A: per-(bucket, block) histogram matrix (bucket-major)
__global__ __launch_bounds__(256) void passA_k(const int* __restrict__ dst, int E,
                                               int* __restrict__ cntMat, int shift,
                                               int nblk, int nbUsed) {
    __shared__ int hist[256];
    hist[threadIdx.x] = 0;
    __syncthreads();
    int base = blockIdx.x * 4096;
#pragma unroll
    for (int r = 0; r < 16; r++) {
        int i = base + threadIdx.x + r * 256;
        if (i < E) atomicAdd(&hist[dst[i] >> shift], 1);
    }
    __syncthreads();
    if (threadIdx.x < nbUsed) cntMat[threadIdx.x * nblk + blockIdx.x] = hist[threadIdx.x];
}

// ---------- generic 3-kernel inclusive scan ----------
__global__ void scanA_k(int* __restrict__ data, int total, int* __restrict__ chunkTot) {
    __shared__ int sd[256];
    int tid = threadIdx.x;
    int base = blockIdx.x * 2048 + tid * 8;
    int v[8]; int s = 0;
#pragma unroll
    for (int r = 0; r < 8; r++) {
        int idx = base + r;
        int x = (idx < total) ? data[idx] : 0;
        s += x; v[r] = s;
    }
    sd[tid] = s; __syncthreads();
    for (int off = 1; off < 256; off <<= 1) {
        int x = (tid >= off) ? sd[tid - off] : 0;
        __syncthreads();
        sd[tid] += x;
        __syncthreads();
    }
    int prev = (tid > 0) ? sd[tid - 1] : 0;
#pragma unroll
    for (int r = 0; r < 8; r++) {
        int idx = base + r;
        if (idx < total) data[idx] = v[r] + prev;
    }
    if (tid == 255) chunkTot[blockIdx.x] = sd[255];
}

__global__ void scanB_k(const int* __restrict__ chunkTot, int nchunk, int* __restrict__ chunkOff) {
    __shared__ int sd[256];
    int tid = threadIdx.x;
    int v = (tid < nchunk) ? chunkTot[tid] : 0;
    sd[tid] = v; __syncthreads();
    for (int off = 1; off < 256; off <<= 1) {
        int x = (tid >= off) ? sd[tid - off] : 0;
        __syncthreads();
        sd[tid] += x;
        __syncthreads();
    }
    if (tid < nchunk) chunkOff[tid] = sd[tid] - v;
}

__global__ void scanC2_k(int* __restrict__ data, int total, const int* __restrict__ chunkOff) {
    int off = chunkOff[blockIdx.x];
    int base = blockIdx.x * 2048 + threadIdx.x * 8;
#pragma unroll
    for (int r = 0; r < 8; r++) {
        int idx = base + r;
        if (idx < total) data[idx] += off;
    }
}

// pass B: LDS counting sort of 4096 edges into bucket-grouped 4B entries,
// destinations from the scanned count matrix (no global atomics).
__global__ __launch_bounds__(256) void passB_k(const int* __restrict__ ei,
                                               const int* __restrict__ ety, int E,
                                               const int* __restrict__ cntScan,
                                               unsigned* __restrict__ binned,
                                               int shift, int sBits, int nblk, int nbUsed) {
    __shared__ unsigned stage[4096];
    __shared__ int bkid[4096];
    __shared__ int hist[256], sd[256], cursor[256], rebase[256];
    int tid = threadIdx.x;
    int base = blockIdx.x * 4096;
    hist[tid] = 0;
    __syncthreads();

    unsigned ent[16];
    int bk[16];
    int lowmask = (1 << shift) - 1;
#pragma unroll
    for (int r = 0; r < 16; r++) {
        int i = base + tid + r * 256;
        if (i < E) {
            int s = ei[i];
            int d = ei[E + i];
            int t = ety[i];
            ent[r] = ((unsigned)(d & lowmask) << (sBits + 1)) | ((unsigned)t << sBits) | (unsigned)s;
            bk[r] = d >> shift;
            atomicAdd(&hist[bk[r]], 1);
        } else bk[r] = -1;
    }
    __syncthreads();

    int h = hist[tid];
    sd[tid] = h; __syncthreads();
    for (int off = 1; off < 256; off <<= 1) {
        int x = (tid >= off) ? sd[tid - off] : 0;
        __syncthreads();
        sd[tid] += x;
        __syncthreads();
    }
    int excl = sd[tid] - h;
    cursor[tid] = excl;
    int gb = 0;
    if (tid < nbUsed && h > 0) gb = cntScan[tid * nblk + blockIdx.x] - h;
    rebase[tid] = gb - excl;
    __syncthreads();

#pragma unroll
    for (int r = 0; r < 16; r++) {
        if (bk[r] >= 0) {
            int p = atomicAdd(&cursor[bk[r]], 1);
            stage[p] = ent[r];
            bkid[p] = bk[r];
        }
    }
    __syncthreads();

    int cnt = E - base; if (cnt > 4096) cnt = 4096;
    for (int i = tid; i < cnt; i += 256)
        binned[rebase[bkid[i]] + i] = stage[i];
}

// pass C: per-bucket LDS counting sort (2 half-bucket phases), fused rowptr,
// fully coalesced writes of the final node-sorted edge list.
__global__ __launch_bounds__(256) void passC_k(const unsigned* __restrict__ binned,
                                               const int* __restrict__ cntScan,
                                               int nblk, int* __restrict__ rowptr,
                                               unsigned* __restrict__ sorted,
                                               int N, int E, int shift, int sBits,
                                               int nbUsed) {
    __shared__ unsigned stage[12288];
    __shared__ int hist[512], cursor[512], sd[256];
    int tid = threadIdx.x;
    int b = blockIdx.x;
    int s = (b == 0) ? 0 : cntScan[b * nblk - 1];
    int e = cntScan[(b + 1) * nblk - 1];
    int nodeBase = b << shift;
    int half = 1 << (shift - 1);
    int dshift = sBits + 1;
    int segBase = s;

    for (int ph = 0; ph < 2; ph++) {
        int lnBase = ph * half;
        hist[tid] = 0; hist[tid + 256] = 0;
        __syncthreads();
        for (int i = s + tid; i < e; i += 256) {
            int ln = (int)(binned[i] >> dshift) - lnBase;
            if (ln >= 0 && ln < half) atomicAdd(&hist[ln], 1);
        }
        __syncthreads();
        int v0 = hist[2 * tid], v1 = hist[2 * tid + 1];
        int sum2 = v0 + v1;
        sd[tid] = sum2; __syncthreads();
        for (int off = 1; off < 256; off <<= 1) {
            int x = (tid >= off) ? sd[tid - off] : 0;
            __syncthreads();
            sd[tid] += x;
            __syncthreads();
        }
        int exclPair = sd[tid] - sum2;
        int total = sd[255];
        __syncthreads();
        hist[2 * tid] = exclPair;
        hist[2 * tid + 1] = exclPair + v0;
        cursor[2 * tid] = exclPair;
        cursor[2 * tid + 1] = exclPair + v0;
        __syncthreads();
        for (int i = s + tid; i < e; i += 256) {
            unsigned en = binned[i];
            int ln = (int)(en >> dshift) - lnBase;
            if (ln >= 0 && ln < half) {
                int p = atomicAdd(&cursor[ln], 1);
                if (p < 12288) stage[p] = en;
            }
        }
        __syncthreads();
        for (int k = tid; k < total; k += 256)
            if (k < 12288) sorted[segBase + k] = stage[k];
        for (int i = tid; i < half; i += 256) {
            int n = nodeBase + lnBase + i;
            if (n < N) rowptr[n] = segBase + hist[i];
        }
        segBase += total;
        __syncthreads();
    }
    if (b == nbUsed - 1 && tid == 0) rowptr[N] = E;
}

__global__ void initpool_k(unsigned* __restrict__ maxb, float* __restrict__ sumb, int n) {
    int i = blockIdx.x * blockDim.x + threadIdx.x;
    if (i < n) { maxb[i] = 0x007FFFFFu; sumb[i] = 0.f; }  // enc(-inf)
}

// ---------- layer A: aggregate + z@W1+b1 + BN partial stats ----------
__global__ __launch_bounds__(256) void layerA_k(
    const float* __restrict__ hin, const int* __restrict__ rowptr,
    const unsigned* __restrict__ sorted, const float* __restrict__ emb,
    const float* __restrict__ W1, const float* __restrict__ b1,
    float* __restrict__ tout, float* __restrict__ partial, int Nn, int sBits)
{
    int tid = threadIdx.x;
    int j = tid & 31, grp = tid >> 5;
    unsigned smask = (1u << sBits) - 1u;
    float w1c[32];
#pragma unroll
    for (int k = 0; k < 32; k++) w1c[k] = W1[k * 32 + j];
    float b1j = b1[j];
    float e0v = emb[j], e1v = emb[32 + j];
    float bsum = 0.f, bsq = 0.f;

    for (int n = blockIdx.x * 8 + grp; n < Nn; n += gridDim.x * 8) {
        float acc = hin[n * 32 + j];
        int es = rowptr[n], ee = rowptr[n + 1];
        for (int e = es; e < ee; e += 32) {
            int r = ee - e; if (r > 32) r = 32;
            unsigned pv = (j < r) ? sorted[e + j] : 0u;
#pragma unroll
            for (int k = 0; k < 32; k++) {
                unsigned p = (unsigned)__shfl((int)pv, k, 32);
                int s = (int)(p & smask);
                float hs = hin[s * 32 + j];
                float ev = ((p >> sBits) & 1u) ? e1v : e0v;
                float rl = fmaxf(hs + ev, 0.f);
                acc += (k < r) ? rl : 0.f;
            }
        }
        float t = b1j;
#pragma unroll
        for (int k = 0; k < 32; k++) t = fmaf(__shfl(acc, k, 32), w1c[k], t);
        tout[n * 32 + j] = t;
        bsum += t; bsq += t * t;
    }

    __shared__ float ls[8][32], lq[8][32];
    ls[grp][j] = bsum; lq[grp][j] = bsq;
    __syncthreads();
    if (tid < 32) {
        float s = 0.f, q = 0.f;
#pragma unroll
        for (int r = 0; r < 8; r++) { s += ls[r][tid]; q += lq[r][tid]; }
        partial[blockIdx.x * 64 + tid] = s;
        partial[blockIdx.x * 64 + 32 + tid] = q;
    }
}

// ---------- BN stat reduce -> a, c ----------
__global__ void bnred_k(const float* __restrict__ partial, int nblk,
                        const float* __restrict__ gamma, const float* __restrict__ beta,
                        float* __restrict__ bn_ac, float invN)
{
    __shared__ float sd[256];
    __shared__ float tot[64];
    int tid = threadIdx.x;
    int j = tid >> 2, sub = tid & 3;
    float s = 0.f;
    for (int b = sub; b < nblk; b += 4) s += partial[b * 64 + j];
    sd[tid] = s; __syncthreads();
    if (sub == 0) tot[j] = sd[tid] + sd[tid + 1] + sd[tid + 2] + sd[tid + 3];
    __syncthreads();
    if (tid < 32) {
        float mu = tot[tid] * invN;
        float var = tot[32 + tid] * invN - mu * mu;
        float a = gamma[tid] * rsqrtf(var + 1e-5f);
        bn_ac[tid] = a;
        bn_ac[32 + tid] = beta[tid] - a * mu;
    }
}

// ---------- layer B: relu(bn(t)) @ W2 + b2 (+relu) ----------
__global__ __launch_bounds__(256) void layerB32_k(
    const float* __restrict__ tin, const float* __restrict__ bn_ac,
    const float* __restrict__ W2, const float* __restrict__ b2,
    float* __restrict__ hout, int Nn, int doRelu)
{
    int tid = threadIdx.x;
    int j = tid & 31, grp = tid >> 5;
    float a = bn_ac[j], c = bn_ac[32 + j];
    float wc[32];
#pragma unroll
    for (int k = 0; k < 32; k++) wc[k] = W2[k * 32 + j];
    float bj = b2[j];
    for (int n = blockIdx.x * 8 + grp; n < Nn; n += gridDim.x * 8) {
        float t = tin[n * 32 + j];
        float u = fmaxf(fmaf(a, t, c), 0.f);
        float o = bj;
#pragma unroll
        for (int k = 0; k < 32; k++) o = fmaf(__shfl(u, k, 32), wc[k], o);
        hout[n * 32 + j] = doRelu ? fmaxf(o, 0.f) : o;
    }
}

__global__ __launch_bounds__(256) void layerB64_k(
    const float* __restrict__ tin, const float* __restrict__ bn_ac,
    const float* __restrict__ W2, const float* __restrict__ b2,
    float* __restrict__ hout, int Nn)
{
    int tid = threadIdx.x;
    int j = tid & 31, grp = tid >> 5;
    float a = bn_ac[j], c = bn_ac[32 + j];
    float wlo[32], whi[32];
#pragma unroll
    for (int k = 0; k < 32; k++) { wlo[k] = W2[k * 64 + j]; whi[k] = W2[k * 64 + 32 + j]; }
    float blo = b2[j], bhi = b2[32 + j];
    for (int n = blockIdx.x * 8 + grp; n < Nn; n += gridDim.x * 8) {
        float t = tin[n * 32 + j];
        float u = fmaxf(fmaf(a, t, c), 0.f);
        float olo = blo, ohi = bhi;
#pragma unroll
        for (int k = 0; k < 32; k++) {
            float uk = __shfl(u, k, 32);
            olo = fmaf(uk, wlo[k], olo);
            ohi = fmaf(uk, whi[k], ohi);
        }
        hout[n * 64 + j] = olo;
        hout[n * 64 + 32 + j] = ohi;
    }
}

// ---------- pooling ----------
__global__ void pool1_k(const float* __restrict__ h5, const int* __restrict__ batch,
                        unsigned* __restrict__ maxb, float* __restrict__ sumb, int Nn)
{
    int ch = threadIdx.x & 63, slot = threadIdx.x >> 6;
    int base = blockIdx.x * 256 + slot * 64;
    int g = -1; float mx = 0.f, sm = 0.f;
    for (int i = 0; i < 64; i++) {
        int node = base + i;
        if (node >= Nn) break;
        int gn = batch[node];
        float v = h5[node * 64 + ch];
        if (gn != g) {
            if (g >= 0) { atomicMax(&maxb[g * 64 + ch], encf(mx)); atomicAdd(&sumb[g * 64 + ch], sm); }
            g = gn; mx = v; sm = v;
        } else { mx = fmaxf(mx, v); sm += v; }
    }
    if (g >= 0) { atomicMax(&maxb[g * 64 + ch], encf(mx)); atomicAdd(&sumb[g * 64 + ch], sm); }
}

__global__ void final_k(const unsigned* __restrict__ maxb, const float* __restrict__ sumb,
                        const int* __restrict__ batch, int Nn, float* __restrict__ out)
{
    int g = blockIdx.x, tid = threadIdx.x;
    int a = 0, b = Nn;
    while (a < b) { int m = (a + b) >> 1; if (batch[m] < g) a = m + 1; else b = m; }
    int lo0 = a;
    a = 0; b = Nn;
    while (a < b) { int m = (a + b) >> 1; if (batch[m] < g + 1) a = m + 1; else b = m; }
    int hi0 = a;
    float inv = 1.f / fmaxf((float)(hi0 - lo0), 1.f);
    if (tid < 64) out[g * 128 + tid] = decf(maxb[g * 64 + tid]);
    else          out[g * 128 + tid] = sumb[g * 64 + (tid - 64)] * inv;
}

extern "C" void kernel_launch(void* const* d_in, const int* in_sizes, int n_in,
                              void* d_out, int out_size, void* d_ws, size_t ws_size,
                              hipStream_t stream) {
    const float* x    = (const float*)d_in[0];
    const int*   ei   = (const int*)d_in[1];
    const int*   ety  = (const int*)d_in[2];
    const int*   batch= (const int*)d_in[3];
    const float* emb  = (const float*)d_in[4];
    const float* W1s  = (const float*)d_in[5];
    const float* b1s  = (const float*)d_in[6];
    const float* g1s  = (const float*)d_in[7];
    const float* be1s = (const float*)d_in[8];
    const float* W2s  = (const float*)d_in[9];
    const float* b2s  = (const float*)d_in[10];
    const float* w15  = (const float*)d_in[11];
    const float* b15  = (const float*)d_in[12];
    const float* g5   = (const float*)d_in[13];
    const float* be5  = (const float*)d_in[14];
    const float* w25  = (const float*)d_in[15];
    const float* b25  = (const float*)d_in[16];

    int N = in_sizes[0] / 32;
    int E = in_sizes[1] / 2;
    int G = out_size / 128;

    int sBits = 1; while ((1 << sBits) < N) sBits++;               // 18 for N=200k
    int shift = 0; while (((N - 1) >> shift) >= 256) shift++;      // 10
    int nbUsed = ((N - 1) >> shift) + 1;                           // 196
    int nblkE = (E + 4095) / 4096;                                 // 977

    char* wsb = (char*)d_ws;
    size_t o = 0;
    size_t h5Bytes = (size_t)N * 64 * 4;
    size_t binBytes = (size_t)E * 4;
    size_t aliasBytes = h5Bytes > binBytes ? h5Bytes : binBytes;
    float*    h5     = (float*)(wsb + o);
    unsigned* binned = (unsigned*)(wsb + o);   // alias: dead before first h5 write
    o += aliasBytes;
    float*    tb     = (float*)(wsb + o); o += (size_t)N * 32 * 4;
    int*      rowptr = (int*)(wsb + o);   o += ((size_t)N + 2) * 4;
    unsigned* sorted = (unsigned*)(wsb + o); o += (size_t)E * 4;
    int*      chunkTot = (int*)(wsb + o); o += 1024;
    int*      chunkOff = (int*)(wsb + o); o += 1024;
    float*    partial  = (float*)(wsb + o); o += (size_t)NBLKA * 64 * 4;
    float*    bn_ac    = (float*)(wsb + o); o += 64 * 4;
    unsigned* maxb     = (unsigned*)(wsb + o); o += (size_t)G * 64 * 4;
    float*    sumb     = (float*)(wsb + o); o += (size_t)G * 64 * 4;
    int*      cntMat   = (int*)(wsb + o); o += (size_t)nbUsed * nblkE * 4;

    // ---- CSR build ----
    passA_k<<<nblkE, 256, 0, stream>>>(ei + E, E, cntMat, shift, nblkE, nbUsed);
    int total2 = nbUsed * nblkE;
    int nchunk2 = (total2 + 2047) / 2048;
    scanA_k<<<nchunk2, 256, 0, stream>>>(cntMat, total2, chunkTot);
    scanB_k<<<1, 256, 0, stream>>>(chunkTot, nchunk2, chunkOff);
    scanC2_k<<<nchunk2, 256, 0, stream>>>(cntMat, total2, chunkOff);
    passB_k<<<nblkE, 256, 0, stream>>>(ei, ety, E, cntMat, binned, shift, sBits, nblkE, nbUsed);
    passC_k<<<nbUsed, 256, 0, stream>>>(binned, cntMat, nblkE, rowptr, sorted, N, E, shift, sBits, nbUsed);
    initpool_k<<<(G * 64 + 255) / 256, 256, 0, stream>>>(maxb, sumb, G * 64);

    // ---- 5 GINE layers ----
    const float* hin = x;
    for (int L = 0; L < 5; ++L) {
        const float* W1 = (L < 4) ? W1s + L * 1024 : w15;
        const float* b1 = (L < 4) ? b1s + L * 32  : b15;
        const float* ga = (L < 4) ? g1s + L * 32  : g5;
        const float* be = (L < 4) ? be1s + L * 32 : be5;
        const float* W2 = (L < 4) ? W2s + L * 1024 : w25;
        const float* b2 = (L < 4) ? b2s + L * 32  : b25;

        layerA_k<<<NBLKA, 256, 0, stream>>>(hin, rowptr, sorted, emb, W1, b1, tb, partial, N, sBits);
        bnred_k<<<1, 256, 0, stream>>>(partial, NBLKA, ga, be, bn_ac, 1.f / (float)N);
        if (L < 4) layerB32_k<<<1024, 256, 0, stream>>>(tb, bn_ac, W2, b2, h5, N, 1);
        else       layerB64_k<<<1024, 256, 0, stream>>>(tb, bn_ac, W2, b2, h5, N);
        hin = h5;
    }

    // ---- pooling ----
    pool1_k<<<(N + 255) / 256, 256, 0, stream>>>(h5, batch, maxb, sumb, N);
    final_k<<<G, 128, 0, stream>>>(maxb, sumb, batch, N, (float*)d_out);
}